// Round 9
// baseline (4278.810 us; speedup 1.0000x reference)
//
#include <hip/hip_runtime.h>

#define HIDDEN 4096
#define INTER 14336
#define NTOK 8192   // B*S = 4*2048

typedef _Float16 half8 __attribute__((ext_vector_type(8)));
typedef float floatx4 __attribute__((ext_vector_type(4)));

#define AS1C(p) ((const __attribute__((address_space(1))) void*)(p))
#define AS3(p)  ((__attribute__((address_space(3))) void*)(p))
#define SBAR()  __builtin_amdgcn_s_barrier()
#define WAIT_VM(N) asm volatile("s_waitcnt vmcnt(" #N ")" ::: "memory")
#define PRIO(x) __builtin_amdgcn_s_setprio(x)
#define MFMA16(A,B,C) __builtin_amdgcn_mfma_f32_16x16x32_f16(A,B,C,0,0,0)

// ---------------- conversion kernels ----------------

__global__ void cvt_w_kernel(const int* __restrict__ src, _Float16* __restrict__ dst, long n) {
    long i0 = ((long)blockIdx.x * blockDim.x + threadIdx.x) * 8;
    long stride = (long)gridDim.x * blockDim.x * 8;
    for (long i = i0; i < n; i += stride) {
        int4 a = *(const int4*)(src + i);
        int4 b = *(const int4*)(src + i + 4);
        half8 h;
        h[0] = (_Float16)a.x; h[1] = (_Float16)a.y; h[2] = (_Float16)a.z; h[3] = (_Float16)a.w;
        h[4] = (_Float16)b.x; h[5] = (_Float16)b.y; h[6] = (_Float16)b.z; h[7] = (_Float16)b.w;
        *(half8*)(dst + i) = h;
    }
}

__global__ void cvt_x_kernel(const float* __restrict__ src, _Float16* __restrict__ dst, long n) {
    long i0 = ((long)blockIdx.x * blockDim.x + threadIdx.x) * 8;
    long stride = (long)gridDim.x * blockDim.x * 8;
    for (long i = i0; i < n; i += stride) {
        float4 a = *(const float4*)(src + i);
        float4 b = *(const float4*)(src + i + 4);
        half8 h;
        h[0] = (_Float16)a.x; h[1] = (_Float16)a.y; h[2] = (_Float16)a.z; h[3] = (_Float16)a.w;
        h[4] = (_Float16)b.x; h[5] = (_Float16)b.y; h[6] = (_Float16)b.z; h[7] = (_Float16)b.w;
        *(half8*)(dst + i) = h;
    }
}

// ---------------- fused gate+up (B direct-to-register, A in LDS) ----------------
// BM=256, BN=128, BK=64, 512 thr (8 waves 2Mx4N). LDS 64KB: 2buf x A 32KB.
// B (weights) have NO cross-wave reuse -> load fragments straight global->VGPR
// at the MFMA fragment address, double-buffered one tile ahead (compiler emits
// the precise vmcnt for the register dependency; loads are a full tile old).
// A staged via global_load_lds + T2 swizzle (4 waves share each A row).
// Per tile: Ph0 {ds aLo(8); SBAR; 32 MFMA; SBAR}, Ph1 {ds aHi(8); SBAR; 32 MFMA;
// WAIT_VM(8) releases only A(t+1)'s 4 stage loads (B(t+1)'s 8 stay in flight); SBAR}.

__global__ __launch_bounds__(512, 2) void gateup_kernel(
        const _Float16* __restrict__ Aptr, const _Float16* __restrict__ Bgp,
        const _Float16* __restrict__ Bup, const float* __restrict__ gsc,
        const float* __restrict__ usc, _Float16* __restrict__ H)
{
    constexpr int KDIM = HIDDEN;
    constexpr int NT = KDIM / 64;      // 64 (even)
    constexpr int NBN = INTER / 128;   // 112
    __shared__ _Float16 sA[2][256 * 64];

    const int tid  = threadIdx.x;
    const int lane = tid & 63;
    const int wid  = tid >> 6;
    const int wr   = wid >> 2;   // 0..1
    const int wc   = wid & 3;    // 0..3

    const int nwg = gridDim.x;
    const int bid = blockIdx.x;
    const int swz = (bid & 7) * (nwg >> 3) + (bid >> 3);
    const int bm = swz / NBN;
    const int bn = swz % NBN;

    // A staging (T2 pre-swizzled source)
    const int srow  = tid >> 3;
    const int sslot = (tid & 7) ^ (srow & 7);
    const _Float16* gA = Aptr + ((long)bm * 256 + srow) * KDIM + sslot * 8;

    // B direct fragment base: row = bn*128 + wc*32 + n*16 + (lane&15),
    // col = t*64 + kh*32 + (lane>>4)*8  (matches MFMA B-frag layout)
    const long brow0 = (long)bn * 128 + wc * 32 + (lane & 15);
    const _Float16* gBg = Bgp + brow0 * KDIM + (lane >> 4) * 8;
    const _Float16* gBu = Bup + brow0 * KDIM + (lane >> 4) * 8;

    // A ds_read offsets (swizzled), row&7 == lane&7
    const int arow = wr * 128 + (lane & 15);
    const int sl0 = ((lane >> 4) ^ (lane & 7)) * 8;
    const int sl1 = ((4 + (lane >> 4)) ^ (lane & 7)) * 8;
    const int aof0 = arow * 64 + sl0, aof1 = arow * 64 + sl1;

    floatx4 ag[8][2] = {};
    floatx4 au[8][2] = {};
    half8 aF[4][2];
    half8 bgP[2][2], buP[2][2], bgQ[2][2], buQ[2][2];

#define STAGE_A(t) do { \
        _Float16* dA = &sA[(t) & 1][tid * 8]; \
        const _Float16* sa = gA + (long)(t) * 64; \
        __builtin_amdgcn_global_load_lds(AS1C(sa),                  AS3(dA),            16, 0, 0); \
        __builtin_amdgcn_global_load_lds(AS1C(sa + 1l * 64 * KDIM), AS3(dA + 1 * 4096), 16, 0, 0); \
        __builtin_amdgcn_global_load_lds(AS1C(sa + 2l * 64 * KDIM), AS3(dA + 2 * 4096), 16, 0, 0); \
        __builtin_amdgcn_global_load_lds(AS1C(sa + 3l * 64 * KDIM), AS3(dA + 3 * 4096), 16, 0, 0); \
    } while (0)

#define LOAD_B(BG, BU, t) do { \
        for (int n_ = 0; n_ < 2; ++n_) \
            for (int kh_ = 0; kh_ < 2; ++kh_) { \
                BG[n_][kh_] = *(const half8*)(gBg + (long)n_ * 16 * KDIM + (long)(t) * 64 + kh_ * 32); \
                BU[n_][kh_] = *(const half8*)(gBu + (long)n_ * 16 * KDIM + (long)(t) * 64 + kh_ * 32); \
            } \
    } while (0)

#define GU_TILE(t, BGC, BUC, BGN, BUN) do { \
        const _Float16* A = &sA[(t) & 1][0]; \
        const bool st = ((t) + 1 < NT); \
        if (st) { STAGE_A((t) + 1); LOAD_B(BGN, BUN, (t) + 1); } \
        /* Ph0 */ \
        for (int m_ = 0; m_ < 4; ++m_) { \
            aF[m_][0] = *(const half8*)(A + aof0 + m_ * 1024); \
            aF[m_][1] = *(const half8*)(A + aof1 + m_ * 1024); \
        } \
        SBAR(); \
        PRIO(1); \
        for (int m_ = 0; m_ < 4; ++m_) \
            for (int n_ = 0; n_ < 2; ++n_) { \
                ag[m_][n_] = MFMA16(aF[m_][0], BGC[n_][0], ag[m_][n_]); \
                ag[m_][n_] = MFMA16(aF[m_][1], BGC[n_][1], ag[m_][n_]); \
                au[m_][n_] = MFMA16(aF[m_][0], BUC[n_][0], au[m_][n_]); \
                au[m_][n_] = MFMA16(aF[m_][1], BUC[n_][1], au[m_][n_]); \
            } \
        PRIO(0); \
        SBAR(); \
        /* Ph1 */ \
        for (int m_ = 0; m_ < 4; ++m_) { \
            aF[m_][0] = *(const half8*)(A + aof0 + (4 + m_) * 1024); \
            aF[m_][1] = *(const half8*)(A + aof1 + (4 + m_) * 1024); \
        } \
        SBAR(); \
        PRIO(1); \
        for (int m_ = 0; m_ < 4; ++m_) \
            for (int n_ = 0; n_ < 2; ++n_) { \
                ag[4 + m_][n_] = MFMA16(aF[m_][0], BGC[n_][0], ag[4 + m_][n_]); \
                ag[4 + m_][n_] = MFMA16(aF[m_][1], BGC[n_][1], ag[4 + m_][n_]); \
                au[4 + m_][n_] = MFMA16(aF[m_][0], BUC[n_][0], au[4 + m_][n_]); \
                au[4 + m_][n_] = MFMA16(aF[m_][1], BUC[n_][1], au[4 + m_][n_]); \
            } \
        PRIO(0); \
        if (st) { WAIT_VM(8); SBAR(); } \
    } while (0)

    // prologue: tile0 A staged + B frags issued
    STAGE_A(0);
    LOAD_B(bgP, buP, 0);
    WAIT_VM(8);    // A(0) landed (4 oldest); B(0) waits happen at first MFMA use
    SBAR();

    for (int t = 0; t < NT; t += 2) {
        GU_TILE(t,     bgP, buP, bgQ, buQ);
        GU_TILE(t + 1, bgQ, buQ, bgP, buP);
    }
#undef GU_TILE
#undef LOAD_B
#undef STAGE_A

    // ---- epilogue: h = silu(g*gs) * (u*us), fp16 ----
    const int orow = bm * 256 + wr * 128 + ((lane >> 4) * 4);
    const int ocol = bn * 128 + wc * 32 + (lane & 15);
#pragma unroll
    for (int n = 0; n < 2; ++n) {
        const int col = ocol + n * 16;
        const float gs = gsc[col];
        const float us = usc[col];
#pragma unroll
        for (int m = 0; m < 8; ++m) {
            const int row = orow + m * 16;
#pragma unroll
            for (int q = 0; q < 4; ++q) {
                const float g = ag[m][n][q] * gs;
                const float u = au[m][n][q] * us;
                H[(long)(row + q) * INTER + col] = (_Float16)(g / (1.0f + __expf(-g)) * u);
            }
        }
    }
}

// ---------------- down GEMM (B direct-to-register, A=H in LDS) ----------------
// 256x256, BK=64. Per wave: 4 n-frags of B (wc*64 rows), direct global->VGPR.

__global__ __launch_bounds__(512, 2) void down_kernel(
        const _Float16* __restrict__ Aptr, const _Float16* __restrict__ Bptr,
        const float* __restrict__ dsc, float* __restrict__ out)
{
    constexpr int KDIM = INTER;
    constexpr int NT = KDIM / 64;     // 224 (even)
    constexpr int NBN = HIDDEN / 256; // 16
    __shared__ _Float16 sA[2][256 * 64];

    const int tid  = threadIdx.x;
    const int lane = tid & 63;
    const int wid  = tid >> 6;
    const int wr   = wid >> 2;
    const int wc   = wid & 3;

    const int nwg = gridDim.x;
    const int bid = blockIdx.x;
    const int swz = (bid & 7) * (nwg >> 3) + (bid >> 3);
    const int bm = swz / NBN;
    const int bn = swz % NBN;

    const int srow  = tid >> 3;
    const int sslot = (tid & 7) ^ (srow & 7);
    const _Float16* gA = Aptr + ((long)bm * 256 + srow) * KDIM + sslot * 8;

    const long brow0 = (long)bn * 256 + wc * 64 + (lane & 15);
    const _Float16* gB = Bptr + brow0 * KDIM + (lane >> 4) * 8;

    const int arow = wr * 128 + (lane & 15);
    const int sl0 = ((lane >> 4) ^ (lane & 7)) * 8;
    const int sl1 = ((4 + (lane >> 4)) ^ (lane & 7)) * 8;
    const int aof0 = arow * 64 + sl0, aof1 = arow * 64 + sl1;

    floatx4 acc[8][4] = {};
    half8 aF[4][2];
    half8 bP[4][2], bQ[4][2];

#define STAGE_A(t) do { \
        _Float16* dA = &sA[(t) & 1][tid * 8]; \
        const _Float16* sa = gA + (long)(t) * 64; \
        __builtin_amdgcn_global_load_lds(AS1C(sa),                  AS3(dA),            16, 0, 0); \
        __builtin_amdgcn_global_load_lds(AS1C(sa + 1l * 64 * KDIM), AS3(dA + 1 * 4096), 16, 0, 0); \
        __builtin_amdgcn_global_load_lds(AS1C(sa + 2l * 64 * KDIM), AS3(dA + 2 * 4096), 16, 0, 0); \
        __builtin_amdgcn_global_load_lds(AS1C(sa + 3l * 64 * KDIM), AS3(dA + 3 * 4096), 16, 0, 0); \
    } while (0)

#define LOAD_B(BB, t) do { \
        for (int n_ = 0; n_ < 4; ++n_) \
            for (int kh_ = 0; kh_ < 2; ++kh_) \
                BB[n_][kh_] = *(const half8*)(gB + (long)n_ * 16 * KDIM + (long)(t) * 64 + kh_ * 32); \
    } while (0)

#define DN_TILE(t, BC, BN_) do { \
        const _Float16* A = &sA[(t) & 1][0]; \
        const bool st = ((t) + 1 < NT); \
        if (st) { STAGE_A((t) + 1); LOAD_B(BN_, (t) + 1); } \
        /* Ph0 */ \
        for (int m_ = 0; m_ < 4; ++m_) { \
            aF[m_][0] = *(const half8*)(A + aof0 + m_ * 1024); \
            aF[m_][1] = *(const half8*)(A + aof1 + m_ * 1024); \
        } \
        SBAR(); \
        PRIO(1); \
        for (int m_ = 0; m_ < 4; ++m_) \
            for (int n_ = 0; n_ < 4; ++n_) { \
                acc[m_][n_] = MFMA16(aF[m_][0], BC[n_][0], acc[m_][n_]); \
                acc[m_][n_] = MFMA16(aF[m_][1], BC[n_][1], acc[m_][n_]); \
            } \
        PRIO(0); \
        SBAR(); \
        /* Ph1 */ \
        for (int m_ = 0; m_ < 4; ++m_) { \
            aF[m_][0] = *(const half8*)(A + aof0 + (4 + m_) * 1024); \
            aF[m_][1] = *(const half8*)(A + aof1 + (4 + m_) * 1024); \
        } \
        SBAR(); \
        PRIO(1); \
        for (int m_ = 0; m_ < 4; ++m_) \
            for (int n_ = 0; n_ < 4; ++n_) { \
                acc[4 + m_][n_] = MFMA16(aF[m_][0], BC[n_][0], acc[4 + m_][n_]); \
                acc[4 + m_][n_] = MFMA16(aF[m_][1], BC[n_][1], acc[4 + m_][n_]); \
            } \
        PRIO(0); \
        if (st) { WAIT_VM(8); SBAR(); } \
    } while (0)

    STAGE_A(0);
    LOAD_B(bP, 0);
    WAIT_VM(8);
    SBAR();

    for (int t = 0; t < NT; t += 2) {
        DN_TILE(t,     bP, bQ);
        DN_TILE(t + 1, bQ, bP);
    }
#undef DN_TILE
#undef LOAD_B
#undef STAGE_A

    const int orow = bm * 256 + wr * 128 + ((lane >> 4) * 4);
    const int ocol = bn * 256 + wc * 64 + (lane & 15);
#pragma unroll
    for (int n = 0; n < 4; ++n) {
        const int col = ocol + n * 16;
        const float sc = dsc[col];
#pragma unroll
        for (int m = 0; m < 8; ++m) {
            const int row = orow + m * 16;
#pragma unroll
            for (int q = 0; q < 4; ++q)
                out[(long)(row + q) * HIDDEN + col] = acc[m][n][q] * sc;
        }
    }
}

// ---------------- launch ----------------

extern "C" void kernel_launch(void* const* d_in, const int* in_sizes, int n_in,
                              void* d_out, int out_size, void* d_ws, size_t ws_size,
                              hipStream_t stream) {
    const float* x   = (const float*)d_in[0];
    const int*   gw  = (const int*)d_in[1];
    const float* gsc = (const float*)d_in[2];
    const int*   uw  = (const int*)d_in[3];
    const float* usc = (const float*)d_in[4];
    const int*   dw  = (const int*)d_in[5];
    const float* dsc = (const float*)d_in[6];
    float* out = (float*)d_out;

    char* ws = (char*)d_ws;
    _Float16* x16  = (_Float16*)(ws);                    //  64 MiB
    _Float16* wg16 = (_Float16*)(ws + 67108864ll);       // 112 MiB
    _Float16* wu16 = (_Float16*)(ws + 184549376ll);      // 112 MiB
    _Float16* wd16 = (_Float16*)(ws + 301989888ll);      // 112 MiB
    _Float16* h16  = (_Float16*)(ws + 419430400ll);      // 224 MiB

    cvt_x_kernel<<<4096, 256, 0, stream>>>(x,  x16,  (long)NTOK * HIDDEN);
    cvt_w_kernel<<<4096, 256, 0, stream>>>(gw, wg16, (long)INTER * HIDDEN);
    cvt_w_kernel<<<4096, 256, 0, stream>>>(uw, wu16, (long)INTER * HIDDEN);
    cvt_w_kernel<<<4096, 256, 0, stream>>>(dw, wd16, (long)HIDDEN * INTER);

    // fused gate+up+SwiGLU: [8192 x 14336], h fp16
    gateup_kernel<<<(NTOK / 256) * (INTER / 128), 512, 0, stream>>>(
        x16, wg16, wu16, gsc, usc, h16);
    // down: [8192 x 4096] = H * Wd^T, fp32 out
    down_kernel<<<(NTOK / 256) * (HIDDEN / 256), 512, 0, stream>>>(
        h16, wd16, dsc, out);
}

// Round 10
// 4011.718 us; speedup vs baseline: 1.0666x; 1.0666x over previous
//
#include <hip/hip_runtime.h>

#define HIDDEN 4096
#define INTER 14336
#define NTOK 8192   // B*S = 4*2048

typedef _Float16 half8 __attribute__((ext_vector_type(8)));
typedef float floatx4 __attribute__((ext_vector_type(4)));

#define AS1C(p) ((const __attribute__((address_space(1))) void*)(p))
#define AS3(p)  ((__attribute__((address_space(3))) void*)(p))
#define SBAR()  __builtin_amdgcn_s_barrier()
#define WAIT_VM0() asm volatile("s_waitcnt vmcnt(0)" ::: "memory")
#define PRIO(x) __builtin_amdgcn_s_setprio(x)
#define MFMA16(A,B,C) __builtin_amdgcn_mfma_f32_16x16x32_f16(A,B,C,0,0,0)

// ---------------- conversion kernels ----------------

__device__ __forceinline__ void cvt8(const int* __restrict__ s, _Float16* __restrict__ d, long i) {
    int4 a = *(const int4*)(s + i);
    int4 b = *(const int4*)(s + i + 4);
    half8 h;
    h[0] = (_Float16)a.x; h[1] = (_Float16)a.y; h[2] = (_Float16)a.z; h[3] = (_Float16)a.w;
    h[4] = (_Float16)b.x; h[5] = (_Float16)b.y; h[6] = (_Float16)b.z; h[7] = (_Float16)b.w;
    *(half8*)(d + i) = h;
}

// all three weight matrices have identical element count; 3 independent
// streams per thread -> more loads in flight, 1 launch instead of 3
__global__ void cvt_w3_kernel(const int* __restrict__ s0, const int* __restrict__ s1,
                              const int* __restrict__ s2, _Float16* __restrict__ d0,
                              _Float16* __restrict__ d1, _Float16* __restrict__ d2, long n) {
    long i0 = ((long)blockIdx.x * blockDim.x + threadIdx.x) * 8;
    long stride = (long)gridDim.x * blockDim.x * 8;
    for (long i = i0; i < n; i += stride) {
        cvt8(s0, d0, i);
        cvt8(s1, d1, i);
        cvt8(s2, d2, i);
    }
}

__global__ void cvt_x_kernel(const float* __restrict__ src, _Float16* __restrict__ dst, long n) {
    long i0 = ((long)blockIdx.x * blockDim.x + threadIdx.x) * 8;
    long stride = (long)gridDim.x * blockDim.x * 8;
    for (long i = i0; i < n; i += stride) {
        float4 a = *(const float4*)(src + i);
        float4 b = *(const float4*)(src + i + 4);
        half8 h;
        h[0] = (_Float16)a.x; h[1] = (_Float16)a.y; h[2] = (_Float16)a.z; h[3] = (_Float16)a.w;
        h[4] = (_Float16)b.x; h[5] = (_Float16)b.y; h[6] = (_Float16)b.z; h[7] = (_Float16)b.w;
        *(half8*)(dst + i) = h;
    }
}

// ---------------- fused gate+up (R4 4-phase; staging completed by P1) ----------------
// BM=256, BN=128, BK=64, 512 thr (8 waves, 2M x 4N).
// LDS 128KB: 2buf x (A 32KB + Bg 16KB + Bu 16KB).
// Phases: P0 g(m0-3) [stage A-h0(t+1)+G(t+1)], P1 g(m4-7) [stage A-h1(t+1)+U(t+1)],
//         P2 u(m0-3), P3 u(m4-7) [vmcnt(0): newest load is >=2 phases (~1100cy) old
//         > ~900cy HBM latency -> drain stall ~0].

__global__ __launch_bounds__(512, 2) void gateup_kernel(
        const _Float16* __restrict__ Aptr, const _Float16* __restrict__ Bgp,
        const _Float16* __restrict__ Bup, const float* __restrict__ gsc,
        const float* __restrict__ usc, _Float16* __restrict__ H)
{
    constexpr int KDIM = HIDDEN;
    constexpr int NT = KDIM / 64;      // 64
    constexpr int NBN = INTER / 128;   // 112
    __shared__ _Float16 sA[2][256 * 64];
    __shared__ _Float16 sG[2][128 * 64];
    __shared__ _Float16 sU[2][128 * 64];

    const int tid  = threadIdx.x;
    const int lane = tid & 63;
    const int wid  = tid >> 6;
    const int wr   = wid >> 2;   // 0..1
    const int wc   = wid & 3;    // 0..3

    const int nwg = gridDim.x;
    const int bid = blockIdx.x;
    const int swz = (bid & 7) * (nwg >> 3) + (bid >> 3);
    const int bm = swz / NBN;
    const int bn = swz % NBN;

    // staging addresses (T2: pre-swizzled global source slot)
    const int srow  = tid >> 3;                  // 0..63
    const int sslot = (tid & 7) ^ (srow & 7);
    const _Float16* gA = Aptr + ((long)bm * 256 + srow) * KDIM + sslot * 8;
    const _Float16* gG = Bgp + ((long)bn * 128 + srow) * KDIM + sslot * 8;
    const _Float16* gU = Bup + ((long)bn * 128 + srow) * KDIM + sslot * 8;

    auto stageA = [&](int t, int half) {   // 16KB half-tile, 2 loads/thread
        _Float16* d = &sA[t & 1][half * 8192 + tid * 8];
        const _Float16* s = gA + (long)half * 128 * KDIM + (long)t * 64;
        __builtin_amdgcn_global_load_lds(AS1C(s), AS3(d), 16, 0, 0);
        __builtin_amdgcn_global_load_lds(AS1C(s + 64 * KDIM), AS3(d + 4096), 16, 0, 0);
    };
    auto stageG = [&](int t) {
        _Float16* d = &sG[t & 1][tid * 8];
        const _Float16* s = gG + (long)t * 64;
        __builtin_amdgcn_global_load_lds(AS1C(s), AS3(d), 16, 0, 0);
        __builtin_amdgcn_global_load_lds(AS1C(s + 64 * KDIM), AS3(d + 4096), 16, 0, 0);
    };
    auto stageU = [&](int t) {
        _Float16* d = &sU[t & 1][tid * 8];
        const _Float16* s = gU + (long)t * 64;
        __builtin_amdgcn_global_load_lds(AS1C(s), AS3(d), 16, 0, 0);
        __builtin_amdgcn_global_load_lds(AS1C(s + 64 * KDIM), AS3(d + 4096), 16, 0, 0);
    };

    // ds_read fragment offsets (elements); row&7 == lane&7 for all frags
    const int arow = wr * 128 + (lane & 15);
    const int brow = wc * 32  + (lane & 15);
    const int sl0 = ((lane >> 4) ^ (lane & 7)) * 8;
    const int sl1 = ((4 + (lane >> 4)) ^ (lane & 7)) * 8;
    const int aof0 = arow * 64 + sl0, aof1 = arow * 64 + sl1;
    const int bof0 = brow * 64 + sl0, bof1 = brow * 64 + sl1;

    floatx4 ag[8][2] = {};
    floatx4 au[8][2] = {};
    half8 a[8][2], bg[2][2], bu[2][2];

    // prologue: tile 0
    stageA(0, 0); stageA(0, 1); stageG(0); stageU(0);
    WAIT_VM0();
    SBAR();

    for (int t = 0; t < NT; ++t) {
        const _Float16* A = &sA[t & 1][0];
        const _Float16* G = &sG[t & 1][0];
        const _Float16* U = &sU[t & 1][0];
        const bool st = (t + 1 < NT);

        // ---- P0: stage A-h0(t+1)+G(t+1); ds aLo + bg; MFMA g m0-3 ----
        if (st) { stageA(t + 1, 0); stageG(t + 1); }
#pragma unroll
        for (int m = 0; m < 4; ++m) {
            a[m][0] = *(const half8*)(A + aof0 + m * 1024);
            a[m][1] = *(const half8*)(A + aof1 + m * 1024);
        }
#pragma unroll
        for (int n = 0; n < 2; ++n) {
            bg[n][0] = *(const half8*)(G + bof0 + n * 1024);
            bg[n][1] = *(const half8*)(G + bof1 + n * 1024);
        }
        SBAR();
        PRIO(1);
#pragma unroll
        for (int m = 0; m < 4; ++m)
#pragma unroll
            for (int n = 0; n < 2; ++n) {
                ag[m][n] = MFMA16(a[m][0], bg[n][0], ag[m][n]);
                ag[m][n] = MFMA16(a[m][1], bg[n][1], ag[m][n]);
            }
        PRIO(0);
        SBAR();

        // ---- P1: stage A-h1(t+1)+U(t+1); ds aHi; MFMA g m4-7 ----
        if (st) { stageA(t + 1, 1); stageU(t + 1); }
#pragma unroll
        for (int m = 4; m < 8; ++m) {
            a[m][0] = *(const half8*)(A + aof0 + m * 1024);
            a[m][1] = *(const half8*)(A + aof1 + m * 1024);
        }
        SBAR();
        PRIO(1);
#pragma unroll
        for (int m = 4; m < 8; ++m)
#pragma unroll
            for (int n = 0; n < 2; ++n) {
                ag[m][n] = MFMA16(a[m][0], bg[n][0], ag[m][n]);
                ag[m][n] = MFMA16(a[m][1], bg[n][1], ag[m][n]);
            }
        PRIO(0);
        SBAR();

        // ---- P2: ds bu; MFMA u m0-3 ----
#pragma unroll
        for (int n = 0; n < 2; ++n) {
            bu[n][0] = *(const half8*)(U + bof0 + n * 1024);
            bu[n][1] = *(const half8*)(U + bof1 + n * 1024);
        }
        SBAR();
        PRIO(1);
#pragma unroll
        for (int m = 0; m < 4; ++m)
#pragma unroll
            for (int n = 0; n < 2; ++n) {
                au[m][n] = MFMA16(a[m][0], bu[n][0], au[m][n]);
                au[m][n] = MFMA16(a[m][1], bu[n][1], au[m][n]);
            }
        PRIO(0);
        SBAR();

        // ---- P3: MFMA u m4-7; drain (loads >=2 phases old) ----
        PRIO(1);
#pragma unroll
        for (int m = 4; m < 8; ++m)
#pragma unroll
            for (int n = 0; n < 2; ++n) {
                au[m][n] = MFMA16(a[m][0], bu[n][0], au[m][n]);
                au[m][n] = MFMA16(a[m][1], bu[n][1], au[m][n]);
            }
        PRIO(0);
        WAIT_VM0();
        SBAR();
    }

    // ---- epilogue: h = silu(g*gs) * (u*us), fp16 ----
    const int orow = bm * 256 + wr * 128 + ((lane >> 4) * 4);
    const int ocol = bn * 128 + wc * 32 + (lane & 15);
#pragma unroll
    for (int n = 0; n < 2; ++n) {
        const int col = ocol + n * 16;
        const float gs = gsc[col];
        const float us = usc[col];
#pragma unroll
        for (int m = 0; m < 8; ++m) {
            const int row = orow + m * 16;
#pragma unroll
            for (int q = 0; q < 4; ++q) {
                const float g = ag[m][n][q] * gs;
                const float u = au[m][n][q] * us;
                H[(long)(row + q) * INTER + col] = (_Float16)(g / (1.0f + __expf(-g)) * u);
            }
        }
    }
}

// ---------------- down GEMM (R4 4-phase 256x256; staging completed by P1) ----------------

__global__ __launch_bounds__(512, 2) void down_kernel(
        const _Float16* __restrict__ Aptr, const _Float16* __restrict__ Bptr,
        const float* __restrict__ dsc, float* __restrict__ out)
{
    constexpr int KDIM = INTER;
    constexpr int NT = KDIM / 64;     // 224
    constexpr int NBN = HIDDEN / 256; // 16
    __shared__ _Float16 sA[2][256 * 64];
    __shared__ _Float16 sB[2][256 * 64];

    const int tid  = threadIdx.x;
    const int lane = tid & 63;
    const int wid  = tid >> 6;
    const int wr   = wid >> 2;
    const int wc   = wid & 3;

    const int nwg = gridDim.x;
    const int bid = blockIdx.x;
    const int swz = (bid & 7) * (nwg >> 3) + (bid >> 3);
    const int bm = swz / NBN;
    const int bn = swz % NBN;

    const int srow  = tid >> 3;
    const int sslot = (tid & 7) ^ (srow & 7);
    const _Float16* gA = Aptr + ((long)bm * 256 + srow) * KDIM + sslot * 8;
    const _Float16* gB = Bptr + ((long)bn * 256 + srow) * KDIM + sslot * 8;

    auto stageA = [&](int t, int half) {
        _Float16* d = &sA[t & 1][half * 8192 + tid * 8];
        const _Float16* s = gA + (long)half * 128 * KDIM + (long)t * 64;
        __builtin_amdgcn_global_load_lds(AS1C(s), AS3(d), 16, 0, 0);
        __builtin_amdgcn_global_load_lds(AS1C(s + 64 * KDIM), AS3(d + 4096), 16, 0, 0);
    };
    auto stageB = [&](int t, int half) {
        _Float16* d = &sB[t & 1][half * 8192 + tid * 8];
        const _Float16* s = gB + (long)half * 128 * KDIM + (long)t * 64;
        __builtin_amdgcn_global_load_lds(AS1C(s), AS3(d), 16, 0, 0);
        __builtin_amdgcn_global_load_lds(AS1C(s + 64 * KDIM), AS3(d + 4096), 16, 0, 0);
    };

    const int arow = wr * 128 + (lane & 15);
    const int brow = wc * 64  + (lane & 15);
    const int sl0 = ((lane >> 4) ^ (lane & 7)) * 8;
    const int sl1 = ((4 + (lane >> 4)) ^ (lane & 7)) * 8;
    const int aof0 = arow * 64 + sl0, aof1 = arow * 64 + sl1;
    const int bof0 = brow * 64 + sl0, bof1 = brow * 64 + sl1;

    floatx4 acc[8][4] = {};
    half8 a[8][2], b[4][2];

    stageA(0, 0); stageA(0, 1); stageB(0, 0); stageB(0, 1);
    WAIT_VM0();
    SBAR();

    for (int t = 0; t < NT; ++t) {
        const _Float16* A = &sA[t & 1][0];
        const _Float16* B = &sB[t & 1][0];
        const bool st = (t + 1 < NT);

        // ---- P0: stage A-h0(t+1)+B-h0(t+1); ds aLo + b01; MFMA m0-3 x n0-1 ----
        if (st) { stageA(t + 1, 0); stageB(t + 1, 0); }
#pragma unroll
        for (int m = 0; m < 4; ++m) {
            a[m][0] = *(const half8*)(A + aof0 + m * 1024);
            a[m][1] = *(const half8*)(A + aof1 + m * 1024);
        }
#pragma unroll
        for (int n = 0; n < 2; ++n) {
            b[n][0] = *(const half8*)(B + bof0 + n * 1024);
            b[n][1] = *(const half8*)(B + bof1 + n * 1024);
        }
        SBAR();
        PRIO(1);
#pragma unroll
        for (int m = 0; m < 4; ++m)
#pragma unroll
            for (int n = 0; n < 2; ++n) {
                acc[m][n] = MFMA16(a[m][0], b[n][0], acc[m][n]);
                acc[m][n] = MFMA16(a[m][1], b[n][1], acc[m][n]);
            }
        PRIO(0);
        SBAR();

        // ---- P1: stage A-h1(t+1)+B-h1(t+1); ds b23; MFMA m0-3 x n2-3 ----
        if (st) { stageA(t + 1, 1); stageB(t + 1, 1); }
#pragma unroll
        for (int n = 2; n < 4; ++n) {
            b[n][0] = *(const half8*)(B + bof0 + n * 1024);
            b[n][1] = *(const half8*)(B + bof1 + n * 1024);
        }
        SBAR();
        PRIO(1);
#pragma unroll
        for (int m = 0; m < 4; ++m)
#pragma unroll
            for (int n = 2; n < 4; ++n) {
                acc[m][n] = MFMA16(a[m][0], b[n][0], acc[m][n]);
                acc[m][n] = MFMA16(a[m][1], b[n][1], acc[m][n]);
            }
        PRIO(0);
        SBAR();

        // ---- P2: ds aHi; MFMA m4-7 x n2-3 ----
#pragma unroll
        for (int m = 4; m < 8; ++m) {
            a[m][0] = *(const half8*)(A + aof0 + m * 1024);
            a[m][1] = *(const half8*)(A + aof1 + m * 1024);
        }
        SBAR();
        PRIO(1);
#pragma unroll
        for (int m = 4; m < 8; ++m)
#pragma unroll
            for (int n = 2; n < 4; ++n) {
                acc[m][n] = MFMA16(a[m][0], b[n][0], acc[m][n]);
                acc[m][n] = MFMA16(a[m][1], b[n][1], acc[m][n]);
            }
        PRIO(0);
        SBAR();

        // ---- P3: MFMA m4-7 x n0-1; drain (loads >=2 phases old) ----
        PRIO(1);
#pragma unroll
        for (int m = 4; m < 8; ++m)
#pragma unroll
            for (int n = 0; n < 2; ++n) {
                acc[m][n] = MFMA16(a[m][0], b[n][0], acc[m][n]);
                acc[m][n] = MFMA16(a[m][1], b[n][1], acc[m][n]);
            }
        PRIO(0);
        WAIT_VM0();
        SBAR();
    }

    const int orow = bm * 256 + wr * 128 + ((lane >> 4) * 4);
    const int ocol = bn * 256 + wc * 64 + (lane & 15);
#pragma unroll
    for (int n = 0; n < 4; ++n) {
        const int col = ocol + n * 16;
        const float sc = dsc[col];
#pragma unroll
        for (int m = 0; m < 8; ++m) {
            const int row = orow + m * 16;
#pragma unroll
            for (int q = 0; q < 4; ++q)
                out[(long)(row + q) * HIDDEN + col] = acc[m][n][q] * sc;
        }
    }
}

// ---------------- launch ----------------

extern "C" void kernel_launch(void* const* d_in, const int* in_sizes, int n_in,
                              void* d_out, int out_size, void* d_ws, size_t ws_size,
                              hipStream_t stream) {
    const float* x   = (const float*)d_in[0];
    const int*   gw  = (const int*)d_in[1];
    const float* gsc = (const float*)d_in[2];
    const int*   uw  = (const int*)d_in[3];
    const float* usc = (const float*)d_in[4];
    const int*   dw  = (const int*)d_in[5];
    const float* dsc = (const float*)d_in[6];
    float* out = (float*)d_out;

    char* ws = (char*)d_ws;
    _Float16* x16  = (_Float16*)(ws);                    //  64 MiB
    _Float16* wg16 = (_Float16*)(ws + 67108864ll);       // 112 MiB
    _Float16* wu16 = (_Float16*)(ws + 184549376ll);      // 112 MiB
    _Float16* wd16 = (_Float16*)(ws + 301989888ll);      // 112 MiB
    _Float16* h16  = (_Float16*)(ws + 419430400ll);      // 224 MiB

    cvt_x_kernel<<<4096, 256, 0, stream>>>(x, x16, (long)NTOK * HIDDEN);
    cvt_w3_kernel<<<4096, 256, 0, stream>>>(gw, uw, dw, wg16, wu16, wd16,
                                            (long)INTER * HIDDEN);

    // fused gate+up+SwiGLU: [8192 x 14336], h fp16
    gateup_kernel<<<(NTOK / 256) * (INTER / 128), 512, 0, stream>>>(
        x16, wg16, wu16, gsc, usc, h16);
    // down: [8192 x 4096] = H * Wd^T, fp32 out
    down_kernel<<<(NTOK / 256) * (HIDDEN / 256), 512, 0, stream>>>(
        h16, wd16, dsc, out);
}

// Round 11
// 3288.079 us; speedup vs baseline: 1.3013x; 1.2201x over previous
//
#include <hip/hip_runtime.h>

#define HIDDEN 4096
#define INTER 14336
#define NTOK 8192   // B*S = 4*2048

typedef _Float16 half8 __attribute__((ext_vector_type(8)));
typedef float floatx4 __attribute__((ext_vector_type(4)));

#define AS1C(p) ((const __attribute__((address_space(1))) void*)(p))
#define AS3(p)  ((__attribute__((address_space(3))) void*)(p))
#define SBAR()  __builtin_amdgcn_s_barrier()
#define LGKM0() do { asm volatile("s_waitcnt lgkmcnt(0)"); __builtin_amdgcn_sched_barrier(0); } while (0)
#define WVM(N)  asm volatile("s_waitcnt vmcnt(" #N ")" ::: "memory")
#define PRIO(x) __builtin_amdgcn_s_setprio(x)
#define MFMA16(A,B,C) __builtin_amdgcn_mfma_f32_16x16x32_f16(A,B,C,0,0,0)

// ---------------- conversion kernels (R4 versions) ----------------

__global__ void cvt_w_kernel(const int* __restrict__ src, _Float16* __restrict__ dst, long n) {
    long i0 = ((long)blockIdx.x * blockDim.x + threadIdx.x) * 8;
    long stride = (long)gridDim.x * blockDim.x * 8;
    for (long i = i0; i < n; i += stride) {
        int4 a = *(const int4*)(src + i);
        int4 b = *(const int4*)(src + i + 4);
        half8 h;
        h[0] = (_Float16)a.x; h[1] = (_Float16)a.y; h[2] = (_Float16)a.z; h[3] = (_Float16)a.w;
        h[4] = (_Float16)b.x; h[5] = (_Float16)b.y; h[6] = (_Float16)b.z; h[7] = (_Float16)b.w;
        *(half8*)(dst + i) = h;
    }
}

__global__ void cvt_x_kernel(const float* __restrict__ src, _Float16* __restrict__ dst, long n) {
    long i0 = ((long)blockIdx.x * blockDim.x + threadIdx.x) * 8;
    long stride = (long)gridDim.x * blockDim.x * 8;
    for (long i = i0; i < n; i += stride) {
        float4 a = *(const float4*)(src + i);
        float4 b = *(const float4*)(src + i + 4);
        half8 h;
        h[0] = (_Float16)a.x; h[1] = (_Float16)a.y; h[2] = (_Float16)a.z; h[3] = (_Float16)a.w;
        h[4] = (_Float16)b.x; h[5] = (_Float16)b.y; h[6] = (_Float16)b.z; h[7] = (_Float16)b.w;
        *(half8*)(dst + i) = h;
    }
}

// ============ m201-style 8-phase port, fused gate+up ============
// BM=256, BN=128, BK=64. 512 thr, 8 waves (2wr x 4wc). Per-wave 128x32 per matrix.
// LDS 128KB: A[2buf][2kh][256x32] 64K, G[2][2][128x32] 32K, U 32K.
// K-half planes: each 16x16x32 MFMA's K=32 lives in ONE plane. Slot swizzle
// (s + (row>>1))&3 on 64B rows (2-way = free); same perm on stage source.
// Phases/tile: F0(kh0,g: ds a8+bg2, stage A-kh1(t+1)), F1(kh0,u: ds bu2,
// stage G/U-kh1(t+1), WVM), F2(kh1,g: ds a8+bg2, stage A-kh0(t+2)),
// F3(kh1,u: ds bu2, stage G/U-kh0(t+2), WVM).
// Ledger: each WVM(8) releases exactly the 4 oldest loads = the halves the next
// phase reads, issued 4-6 phases (~2400cy) earlier. Tails: F1-end t=NT-1 ->
// WVM(0); F3-end t=NT-2 -> WVM(4), t=NT-1 -> skip.

__global__ __launch_bounds__(512, 2) void gateup_kernel(
        const _Float16* __restrict__ Aptr, const _Float16* __restrict__ Bgp,
        const _Float16* __restrict__ Bup, const float* __restrict__ gsc,
        const float* __restrict__ usc, _Float16* __restrict__ H)
{
    constexpr int KDIM = HIDDEN;
    constexpr int NT = KDIM / 64;      // 64
    constexpr int NBN = INTER / 128;   // 112
    __shared__ _Float16 sA[2][2][256 * 32];
    __shared__ _Float16 sG[2][2][128 * 32];
    __shared__ _Float16 sU[2][2][128 * 32];

    const int tid  = threadIdx.x;
    const int lane = tid & 63;
    const int wid  = tid >> 6;
    const int wr   = wid >> 2;   // 0..1
    const int wc   = wid & 3;    // 0..3

    const int nwg = gridDim.x;
    const int bid = blockIdx.x;
    const int swz = (bid & 7) * (nwg >> 3) + (bid >> 3);
    const int bm = swz / NBN;
    const int bn = swz % NBN;

    // ---- staging: dest is linear (tid*16B); source slot inverse-permuted ----
    const int ssrc = ((tid & 3) - ((tid >> 3) & 3)) & 3;     // logical slot for phys slot tid&3
    const _Float16* gA = Aptr + ((long)bm * 256 + (tid >> 2)) * KDIM + ssrc * 8;
    const _Float16* gG = Bgp + ((long)bn * 128 + (tid >> 2)) * KDIM + ssrc * 8;
    const _Float16* gU = Bup + ((long)bn * 128 + (tid >> 2)) * KDIM + ssrc * 8;

    auto stA = [&](int tt, int kh) {   // 16KB half: 2 loads (rows 0-127, 128-255)
        _Float16* d = &sA[tt & 1][kh][tid * 8];
        const _Float16* s = gA + (long)tt * 64 + kh * 32;
        __builtin_amdgcn_global_load_lds(AS1C(s), AS3(d), 16, 0, 0);
        __builtin_amdgcn_global_load_lds(AS1C(s + 128l * KDIM), AS3(d + 4096), 16, 0, 0);
    };
    auto stG = [&](int tt, int kh) {   // 8KB half: 1 load
        __builtin_amdgcn_global_load_lds(AS1C(gG + (long)tt * 64 + kh * 32),
                                         AS3(&sG[tt & 1][kh][tid * 8]), 16, 0, 0);
    };
    auto stU = [&](int tt, int kh) {
        __builtin_amdgcn_global_load_lds(AS1C(gU + (long)tt * 64 + kh * 32),
                                         AS3(&sU[tt & 1][kh][tid * 8]), 16, 0, 0);
    };

    // ---- ds_read offsets within a kh-plane; swizzle const per lane ----
    const int r15 = lane & 15;
    const int C = (((lane >> 4) + ((r15 >> 1) & 3)) & 3) * 8;
    int aofs[8], bofs[2];
#pragma unroll
    for (int m = 0; m < 8; ++m) aofs[m] = (wr * 128 + m * 16 + r15) * 32 + C;
#pragma unroll
    for (int n = 0; n < 2; ++n) bofs[n] = (wc * 32 + n * 16 + r15) * 32 + C;

    floatx4 ag[8][2] = {};
    floatx4 au[8][2] = {};
    half8 a[8], bg[2], bu[2];

    // ---- prologue: t0 all 6 halves + t1 kh0 halves, in release order ----
    stA(0, 0); stG(0, 0); stU(0, 0);      // loads 1-4
    stA(0, 1); stG(0, 1); stU(0, 1);      // loads 5-8
    stA(1, 0); stG(1, 0); stU(1, 0);      // loads 9-12
    WVM(8);                               // t0-kh0 landed
    SBAR();

    for (int t = 0; t < NT; ++t) {
        const int bf = t & 1;
        const _Float16* A0 = &sA[bf][0][0];
        const _Float16* A1 = &sA[bf][1][0];
        const _Float16* G0 = &sG[bf][0][0];
        const _Float16* G1 = &sG[bf][1][0];
        const _Float16* U0 = &sU[bf][0][0];
        const _Float16* U1 = &sU[bf][1][0];

        // ---- F0 (kh0, g) ----
#pragma unroll
        for (int m = 0; m < 8; ++m) a[m] = *(const half8*)(A0 + aofs[m]);
#pragma unroll
        for (int n = 0; n < 2; ++n) bg[n] = *(const half8*)(G0 + bofs[n]);
        if (t + 1 < NT) stA(t + 1, 1);
        SBAR(); LGKM0();
        PRIO(1);
#pragma unroll
        for (int m = 0; m < 8; ++m)
#pragma unroll
            for (int n = 0; n < 2; ++n) ag[m][n] = MFMA16(a[m], bg[n], ag[m][n]);
        PRIO(0);
        SBAR();

        // ---- F1 (kh0, u) ----
#pragma unroll
        for (int n = 0; n < 2; ++n) bu[n] = *(const half8*)(U0 + bofs[n]);
        if (t + 1 < NT) { stG(t + 1, 1); stU(t + 1, 1); }
        SBAR(); LGKM0();
        PRIO(1);
#pragma unroll
        for (int m = 0; m < 8; ++m)
#pragma unroll
            for (int n = 0; n < 2; ++n) au[m][n] = MFMA16(a[m], bu[n], au[m][n]);
        PRIO(0);
        if (t + 1 < NT) { WVM(8); } else { WVM(0); }   // release kh1(t) halves
        SBAR();

        // ---- F2 (kh1, g) ----
#pragma unroll
        for (int m = 0; m < 8; ++m) a[m] = *(const half8*)(A1 + aofs[m]);
#pragma unroll
        for (int n = 0; n < 2; ++n) bg[n] = *(const half8*)(G1 + bofs[n]);
        if (t + 2 < NT) stA(t + 2, 0);                 // own buf kh0: free after F1
        SBAR(); LGKM0();
        PRIO(1);
#pragma unroll
        for (int m = 0; m < 8; ++m)
#pragma unroll
            for (int n = 0; n < 2; ++n) ag[m][n] = MFMA16(a[m], bg[n], ag[m][n]);
        PRIO(0);
        SBAR();

        // ---- F3 (kh1, u) ----
#pragma unroll
        for (int n = 0; n < 2; ++n) bu[n] = *(const half8*)(U1 + bofs[n]);
        if (t + 2 < NT) { stG(t + 2, 0); stU(t + 2, 0); }
        SBAR(); LGKM0();
        PRIO(1);
#pragma unroll
        for (int m = 0; m < 8; ++m)
#pragma unroll
            for (int n = 0; n < 2; ++n) au[m][n] = MFMA16(a[m], bu[n], au[m][n]);
        PRIO(0);
        if (t + 2 < NT)      { WVM(8); }   // release kh0(t+1) halves
        else if (t + 1 < NT) { WVM(4); }
        SBAR();
    }

    // ---- epilogue: h = silu(g*gs) * (u*us), fp16 (R4-identical) ----
    const int orow = bm * 256 + wr * 128 + ((lane >> 4) * 4);
    const int ocol = bn * 128 + wc * 32 + (lane & 15);
#pragma unroll
    for (int n = 0; n < 2; ++n) {
        const int col = ocol + n * 16;
        const float gs = gsc[col];
        const float us = usc[col];
#pragma unroll
        for (int m = 0; m < 8; ++m) {
            const int row = orow + m * 16;
#pragma unroll
            for (int q = 0; q < 4; ++q) {
                const float g = ag[m][n][q] * gs;
                const float u = au[m][n][q] * us;
                H[(long)(row + q) * INTER + col] = (_Float16)(g / (1.0f + __expf(-g)) * u);
            }
        }
    }
}

// ============ m201-style 8-phase port, down (256x256) ============
// Phases: F0(kh0: ds a8+b01, stage A-kh1(t+1)), F1(kh0: ds b23, stage B-kh1(t+1),
// WVM), F2(kh1: ds a8+b01, stage A-kh0(t+2)), F3(kh1: ds b23, stage B-kh0(t+2), WVM).

__global__ __launch_bounds__(512, 2) void down_kernel(
        const _Float16* __restrict__ Aptr, const _Float16* __restrict__ Bptr,
        const float* __restrict__ dsc, float* __restrict__ out)
{
    constexpr int KDIM = INTER;
    constexpr int NT = KDIM / 64;     // 224
    constexpr int NBN = HIDDEN / 256; // 16
    __shared__ _Float16 sA[2][2][256 * 32];
    __shared__ _Float16 sB[2][2][256 * 32];

    const int tid  = threadIdx.x;
    const int lane = tid & 63;
    const int wid  = tid >> 6;
    const int wr   = wid >> 2;
    const int wc   = wid & 3;

    const int nwg = gridDim.x;
    const int bid = blockIdx.x;
    const int swz = (bid & 7) * (nwg >> 3) + (bid >> 3);
    const int bm = swz / NBN;
    const int bn = swz % NBN;

    const int ssrc = ((tid & 3) - ((tid >> 3) & 3)) & 3;
    const _Float16* gA = Aptr + ((long)bm * 256 + (tid >> 2)) * KDIM + ssrc * 8;
    const _Float16* gB = Bptr + ((long)bn * 256 + (tid >> 2)) * KDIM + ssrc * 8;

    auto stA = [&](int tt, int kh) {
        _Float16* d = &sA[tt & 1][kh][tid * 8];
        const _Float16* s = gA + (long)tt * 64 + kh * 32;
        __builtin_amdgcn_global_load_lds(AS1C(s), AS3(d), 16, 0, 0);
        __builtin_amdgcn_global_load_lds(AS1C(s + 128l * KDIM), AS3(d + 4096), 16, 0, 0);
    };
    auto stB = [&](int tt, int kh) {
        _Float16* d = &sB[tt & 1][kh][tid * 8];
        const _Float16* s = gB + (long)tt * 64 + kh * 32;
        __builtin_amdgcn_global_load_lds(AS1C(s), AS3(d), 16, 0, 0);
        __builtin_amdgcn_global_load_lds(AS1C(s + 128l * KDIM), AS3(d + 4096), 16, 0, 0);
    };

    const int r15 = lane & 15;
    const int C = (((lane >> 4) + ((r15 >> 1) & 3)) & 3) * 8;
    int aofs[8], bofs[4];
#pragma unroll
    for (int m = 0; m < 8; ++m) aofs[m] = (wr * 128 + m * 16 + r15) * 32 + C;
#pragma unroll
    for (int n = 0; n < 4; ++n) bofs[n] = (wc * 64 + n * 16 + r15) * 32 + C;

    floatx4 acc[8][4] = {};
    half8 a[8], b[2];

    // prologue: t0 4 halves + t1 kh0 halves
    stA(0, 0); stB(0, 0);     // loads 1-4
    stA(0, 1); stB(0, 1);     // loads 5-8
    stA(1, 0); stB(1, 0);     // loads 9-12
    WVM(8);
    SBAR();

    for (int t = 0; t < NT; ++t) {
        const int bf = t & 1;
        const _Float16* A0 = &sA[bf][0][0];
        const _Float16* A1 = &sA[bf][1][0];
        const _Float16* B0 = &sB[bf][0][0];
        const _Float16* B1 = &sB[bf][1][0];

        // ---- F0 (kh0, n01) ----
#pragma unroll
        for (int m = 0; m < 8; ++m) a[m] = *(const half8*)(A0 + aofs[m]);
#pragma unroll
        for (int n = 0; n < 2; ++n) b[n] = *(const half8*)(B0 + bofs[n]);
        if (t + 1 < NT) stA(t + 1, 1);
        SBAR(); LGKM0();
        PRIO(1);
#pragma unroll
        for (int m = 0; m < 8; ++m)
#pragma unroll
            for (int n = 0; n < 2; ++n) acc[m][n] = MFMA16(a[m], b[n], acc[m][n]);
        PRIO(0);
        SBAR();

        // ---- F1 (kh0, n23) ----
#pragma unroll
        for (int n = 0; n < 2; ++n) b[n] = *(const half8*)(B0 + bofs[2 + n]);
        if (t + 1 < NT) stB(t + 1, 1);
        SBAR(); LGKM0();
        PRIO(1);
#pragma unroll
        for (int m = 0; m < 8; ++m)
#pragma unroll
            for (int n = 0; n < 2; ++n) acc[m][2 + n] = MFMA16(a[m], b[n], acc[m][2 + n]);
        PRIO(0);
        if (t + 1 < NT) { WVM(8); } else { WVM(0); }
        SBAR();

        // ---- F2 (kh1, n01) ----
#pragma unroll
        for (int m = 0; m < 8; ++m) a[m] = *(const half8*)(A1 + aofs[m]);
#pragma unroll
        for (int n = 0; n < 2; ++n) b[n] = *(const half8*)(B1 + bofs[n]);
        if (t + 2 < NT) stA(t + 2, 0);
        SBAR(); LGKM0();
        PRIO(1);
#pragma unroll
        for (int m = 0; m < 8; ++m)
#pragma unroll
            for (int n = 0; n < 2; ++n) acc[m][n] = MFMA16(a[m], b[n], acc[m][n]);
        PRIO(0);
        SBAR();

        // ---- F3 (kh1, n23) ----
#pragma unroll
        for (int n = 0; n < 2; ++n) b[n] = *(const half8*)(B1 + bofs[2 + n]);
        if (t + 2 < NT) stB(t + 2, 0);
        SBAR(); LGKM0();
        PRIO(1);
#pragma unroll
        for (int m = 0; m < 8; ++m)
#pragma unroll
            for (int n = 0; n < 2; ++n) acc[m][2 + n] = MFMA16(a[m], b[n], acc[m][2 + n]);
        PRIO(0);
        if (t + 2 < NT)      { WVM(8); }
        else if (t + 1 < NT) { WVM(4); }
        SBAR();
    }

    const int orow = bm * 256 + wr * 128 + ((lane >> 4) * 4);
    const int ocol = bn * 256 + wc * 64 + (lane & 15);
#pragma unroll
    for (int n = 0; n < 4; ++n) {
        const int col = ocol + n * 16;
        const float sc = dsc[col];
#pragma unroll
        for (int m = 0; m < 8; ++m) {
            const int row = orow + m * 16;
#pragma unroll
            for (int q = 0; q < 4; ++q)
                out[(long)(row + q) * HIDDEN + col] = acc[m][n][q] * sc;
        }
    }
}

// ---------------- launch ----------------

extern "C" void kernel_launch(void* const* d_in, const int* in_sizes, int n_in,
                              void* d_out, int out_size, void* d_ws, size_t ws_size,
                              hipStream_t stream) {
    const float* x   = (const float*)d_in[0];
    const int*   gw  = (const int*)d_in[1];
    const float* gsc = (const float*)d_in[2];
    const int*   uw  = (const int*)d_in[3];
    const float* usc = (const float*)d_in[4];
    const int*   dw  = (const int*)d_in[5];
    const float* dsc = (const float*)d_in[6];
    float* out = (float*)d_out;

    char* ws = (char*)d_ws;
    _Float16* x16  = (_Float16*)(ws);                    //  64 MiB
    _Float16* wg16 = (_Float16*)(ws + 67108864ll);       // 112 MiB
    _Float16* wu16 = (_Float16*)(ws + 184549376ll);      // 112 MiB
    _Float16* wd16 = (_Float16*)(ws + 301989888ll);      // 112 MiB
    _Float16* h16  = (_Float16*)(ws + 419430400ll);      // 224 MiB

    cvt_x_kernel<<<4096, 256, 0, stream>>>(x,  x16,  (long)NTOK * HIDDEN);
    cvt_w_kernel<<<4096, 256, 0, stream>>>(gw, wg16, (long)INTER * HIDDEN);
    cvt_w_kernel<<<4096, 256, 0, stream>>>(uw, wu16, (long)INTER * HIDDEN);
    cvt_w_kernel<<<4096, 256, 0, stream>>>(dw, wd16, (long)HIDDEN * INTER);

    gateup_kernel<<<(NTOK / 256) * (INTER / 128), 512, 0, stream>>>(
        x16, wg16, wu16, gsc, usc, h16);
    down_kernel<<<(NTOK / 256) * (HIDDEN / 256), 512, 0, stream>>>(
        h16, wd16, dsc, out);
}